// Round 1
// baseline (519.811 us; speedup 1.0000x reference)
//
#include <hip/hip_runtime.h>
#include <math.h>

#define N_NODES 50000
#define N_EDGES 800000
#define IN_FEATS 128
#define N_HIDDEN 64
#define OUT_FEATS 40
#define DIM 8

// ---------------- Kernel 1: per-edge gaussian weights for both layers ----------------
__global__ void gw_kernel(const float* __restrict__ ew,
                          const float* __restrict__ mu1, const float* __restrict__ is1,
                          const float* __restrict__ mu2, const float* __restrict__ is2,
                          float* __restrict__ g1, float* __restrict__ g2) {
    int e = blockIdx.x * blockDim.x + threadIdx.x;
    if (e >= N_EDGES) return;
    float s1 = 0.f, s2 = 0.f;
#pragma unroll
    for (int d = 0; d < DIM; ++d) {
        float v = ew[e * DIM + d];
        float d1 = v - mu1[d]; float a1 = is1[d];
        float d2 = v - mu2[d]; float a2 = is2[d];
        s1 += d1 * d1 * a1 * a1;
        s2 += d2 * d2 * a2 * a2;
    }
    g1[e] = expf(-0.5f * s1);
    g2[e] = expf(-0.5f * s2);
}

// ---------------- Kernel 2: h1 = features @ W1  [N,128]x[128,64] ----------------
__global__ __launch_bounds__(64) void gemm1_kernel(const float* __restrict__ x,
                                                   const float* __restrict__ W,
                                                   float* __restrict__ h) {
    __shared__ float xs[IN_FEATS];
    int n = blockIdx.x;
    int t = threadIdx.x;
    xs[t]      = x[n * IN_FEATS + t];
    xs[t + 64] = x[n * IN_FEATS + t + 64];
    __syncthreads();
    float acc = 0.f;
#pragma unroll
    for (int k = 0; k < IN_FEATS; ++k)
        acc += xs[k] * W[k * N_HIDDEN + t];
    h[n * N_HIDDEN + t] = acc;
}

// ---------------- Kernel 3a: init x1 rows with bias b1 ----------------
__global__ void init_x1_kernel(const float* __restrict__ b, float* __restrict__ x1) {
    int i = blockIdx.x * blockDim.x + threadIdx.x;
    if (i >= N_NODES * N_HIDDEN) return;
    x1[i] = b[i & (N_HIDDEN - 1)];
}

// ---------------- Kernel 3b: scatter layer 1 ----------------
__global__ void scatter1_kernel(const float* __restrict__ h,
                                const float* __restrict__ g,
                                const int* __restrict__ src,
                                const int* __restrict__ dst,
                                float* __restrict__ agg) {
    int gt = blockIdx.x * blockDim.x + threadIdx.x;   // < 800000*64 = 51.2M, fits int
    int e = gt >> 6;
    int f = gt & 63;
    if (e >= N_EDGES) return;
    float val = h[src[e] * N_HIDDEN + f] * g[e];
    atomicAdd(&agg[dst[e] * N_HIDDEN + f], val);
}

// ---------------- Kernel 4: h2 = x1 @ W2  [N,64]x[64,40] ----------------
__global__ __launch_bounds__(64) void gemm2_kernel(const float* __restrict__ x,
                                                   const float* __restrict__ W,
                                                   float* __restrict__ h) {
    __shared__ float xs[N_HIDDEN];
    int n = blockIdx.x;
    int t = threadIdx.x;
    xs[t] = x[n * N_HIDDEN + t];
    __syncthreads();
    if (t < OUT_FEATS) {
        float acc = 0.f;
#pragma unroll
        for (int k = 0; k < N_HIDDEN; ++k)
            acc += xs[k] * W[k * OUT_FEATS + t];
        h[n * OUT_FEATS + t] = acc;
    }
}

// ---------------- Kernel 5a: init out rows with bias b2 ----------------
__global__ void init_out_kernel(const float* __restrict__ b, float* __restrict__ out) {
    int i = blockIdx.x * blockDim.x + threadIdx.x;
    if (i >= N_NODES * OUT_FEATS) return;
    out[i] = b[i % OUT_FEATS];
}

// ---------------- Kernel 5b: scatter layer 2 (320 threads = 8 edges x 40 feats) ----------------
__global__ void scatter2_kernel(const float* __restrict__ h,
                                const float* __restrict__ g,
                                const int* __restrict__ src,
                                const int* __restrict__ dst,
                                float* __restrict__ out) {
    int t = threadIdx.x;
    int e = blockIdx.x * 8 + t / OUT_FEATS;
    int f = t % OUT_FEATS;
    if (e >= N_EDGES) return;
    float val = h[src[e] * OUT_FEATS + f] * g[e];
    atomicAdd(&out[dst[e] * OUT_FEATS + f], val);
}

// ---------------- Kernel 6: in-place log_softmax per row (one wave per node) ----------------
__global__ __launch_bounds__(64) void logsoftmax_kernel(float* __restrict__ out) {
    int n = blockIdx.x;
    int t = threadIdx.x;
    float v = (t < OUT_FEATS) ? out[n * OUT_FEATS + t] : -INFINITY;
    float m = v;
#pragma unroll
    for (int off = 32; off; off >>= 1)
        m = fmaxf(m, __shfl_xor(m, off, 64));
    float ex = (t < OUT_FEATS) ? expf(v - m) : 0.f;
    float s = ex;
#pragma unroll
    for (int off = 32; off; off >>= 1)
        s += __shfl_xor(s, off, 64);
    if (t < OUT_FEATS)
        out[n * OUT_FEATS + t] = v - m - logf(s);
}

extern "C" void kernel_launch(void* const* d_in, const int* in_sizes, int n_in,
                              void* d_out, int out_size, void* d_ws, size_t ws_size,
                              hipStream_t stream) {
    const float* features   = (const float*)d_in[0];
    const float* edge_weight= (const float*)d_in[1];
    const int*   src        = (const int*)d_in[2];
    const int*   dst        = (const int*)d_in[3];
    const float* W1         = (const float*)d_in[4];
    const float* b1         = (const float*)d_in[5];
    const float* mu1        = (const float*)d_in[6];
    const float* is1        = (const float*)d_in[7];
    const float* W2         = (const float*)d_in[8];
    const float* b2         = (const float*)d_in[9];
    const float* mu2        = (const float*)d_in[10];
    const float* is2        = (const float*)d_in[11];
    float* out = (float*)d_out;

    // Workspace layout (floats): h1[3.2M] | x1[3.2M] | h2[2M] | g1[0.8M] | g2[0.8M]  = 40 MB
    float* ws = (float*)d_ws;
    float* h1 = ws;
    float* x1 = h1 + (size_t)N_NODES * N_HIDDEN;
    float* h2 = x1 + (size_t)N_NODES * N_HIDDEN;
    float* g1 = h2 + (size_t)N_NODES * OUT_FEATS;
    float* g2 = g1 + (size_t)N_EDGES;

    // 1. edge gaussian weights (both layers)
    gw_kernel<<<(N_EDGES + 255) / 256, 256, 0, stream>>>(edge_weight, mu1, is1, mu2, is2, g1, g2);

    // 2. h1 = features @ W1
    gemm1_kernel<<<N_NODES, 64, 0, stream>>>(features, W1, h1);

    // 3. x1 = segment_sum(h1[src]*g1, dst) + b1
    init_x1_kernel<<<(N_NODES * N_HIDDEN + 255) / 256, 256, 0, stream>>>(b1, x1);
    scatter1_kernel<<<(N_EDGES * 64) / 256, 256, 0, stream>>>(h1, g1, src, dst, x1);

    // 4. h2 = x1 @ W2
    gemm2_kernel<<<N_NODES, 64, 0, stream>>>(x1, W2, h2);

    // 5. out = segment_sum(h2[src]*g2, dst) + b2
    init_out_kernel<<<(N_NODES * OUT_FEATS + 255) / 256, 256, 0, stream>>>(b2, out);
    scatter2_kernel<<<(N_EDGES + 7) / 8, 320, 0, stream>>>(h2, g2, src, dst, out);

    // 6. log_softmax rows, in place
    logsoftmax_kernel<<<N_NODES, 64, 0, stream>>>(out);
}